// Round 13
// baseline (92.771 us; speedup 1.0000x reference)
//
#include <hip/hip_runtime.h>
#include <hip/hip_bf16.h>

typedef __attribute__((ext_vector_type(8))) short bf16x8;
typedef __attribute__((ext_vector_type(4))) float f32x4;
typedef unsigned short u16;
typedef unsigned int u32;

#define B_ 2
#define S_ 2048
#define D_ 1024
#define H_ 16
#define HD_ 64

#define LOG2E 1.44269504088896340736f

__device__ __forceinline__ u16 f2bf(float f) {
    __hip_bfloat16 h = __float2bfloat16(f);
    u16 r;
    __builtin_memcpy(&r, &h, 2);
    return r;
}

__device__ __forceinline__ float ex2(float x) {
    float r;
    asm("v_exp_f32 %0, %1" : "=v"(r) : "v"(x));
    return r;
}

__device__ __forceinline__ void gload16(const u16* gsrc, u16* lds_base) {
    __builtin_amdgcn_global_load_lds(
        (const __attribute__((address_space(1))) void*)gsrc,
        (__attribute__((address_space(3))) void*)lds_base, 16, 0, 0);
}

// ---------------- prep: x->bf16, w_attn^T->bf16, w_proj^T->bf16 (1 launch) --
__global__ __launch_bounds__(256) void prep(
    const float* __restrict__ x, u16* __restrict__ x_bf,
    const float* __restrict__ wa, u16* __restrict__ waT,
    const float* __restrict__ wp, u16* __restrict__ wpT) {
    __shared__ float t[32][33];
    const int bid = blockIdx.x;
    const int tid = threadIdx.x;
    if (bid < 4096) {
        int i = bid * 256 + tid;
        float4 v = ((const float4*)x)[i];
        ushort4 o;
        o.x = f2bf(v.x); o.y = f2bf(v.y); o.z = f2bf(v.z); o.w = f2bf(v.w);
        ((ushort4*)x_bf)[i] = o;
        return;
    }
    const float* in;
    u16* out;
    int R = 1024, C, bx, by;
    if (bid < 4096 + 3072) {
        in = wa; out = waT; C = 3072;
        int idx = bid - 4096;
        bx = idx % 96; by = idx / 96;
    } else {
        in = wp; out = wpT; C = 1024;
        int idx = bid - 7168;
        bx = idx % 32; by = idx / 32;
    }
    const int c0 = bx * 32, r0 = by * 32;
    const int lx = tid & 31, ly = tid >> 5;
#pragma unroll
    for (int i = 0; i < 4; ++i)
        t[ly + i * 8][lx] = in[(size_t)(r0 + ly + i * 8) * C + c0 + lx];
    __syncthreads();
#pragma unroll
    for (int i = 0; i < 4; ++i)
        out[(size_t)(c0 + ly + i * 8) * R + r0 + lx] = f2bf(t[lx][ly + i * 8]);
}

// ====== GEMM1: 128x192 tile, grid 512 (2 blocks/CU), 4-phase vmcnt =========
// A [4096][1024] bf16, Bt [3072][1024] bf16. 8 waves (2M x 4N), per-wave
// 64x48. LDS 80KB: Al[2][128*64], Bl[2][192*64]. Stage units/tile/wave:
// SA=2, SB=3. Ledger: prologue {T0.SB,T0.SA,T1.SB} vmcnt(3); p0 +T1.SA,
// p1 +T2.SB vmcnt(3), p2 +T2.SA, p3 +T3.SB vmcnt(3). Two blocks per CU
// cross-hide each other's barrier/vmcnt stalls.
__global__ __launch_bounds__(512, 4) void gemm192b(
    const u16* __restrict__ A, const u16* __restrict__ Bt,
    const float* __restrict__ bias,
    u16* __restrict__ oQ, u16* __restrict__ oK, u16* __restrict__ oV) {
    extern __shared__ u16 lds[];
    u16* Al[2] = {lds, lds + 8192};                  // 128*64 each
    u16* Bl[2] = {lds + 16384, lds + 16384 + 12288}; // 192*64 each

    const int tid = threadIdx.x;
    const int lane = tid & 63, w = tid >> 6;         // 8 waves
    const int wm = w >> 2, wn = w & 3;               // wave: 64m x 48n
    const int l15 = lane & 15, lg = lane >> 4;
    // XCD-chunked swizzle over 512 blocks (64/XCD: 4 m-rows x 16 n)
    const int lin = blockIdx.y * 16 + blockIdx.x;
    const int nl = (lin & 7) * 64 + (lin >> 3);
    const int m0 = (nl >> 4) * 128, n0 = (nl & 15) * 192;

    const int lrow = lane >> 3;
    const int csrc = ((lane & 7) * 8) ^ ((lrow & 7) * 8);
    const u16* pA = A + (size_t)(m0 + w * 16 + lrow) * 1024 + csrc;
    const u16* pB = Bt + (size_t)(n0 + w * 24 + lrow) * 1024 + csrc;

    const int sw8 = (l15 & 7) * 8;
    const int c0 = (lg * 8) ^ sw8;
    const int c1 = (32 + lg * 8) ^ sw8;
    const int abase = (wm * 64 + l15) * 64;
    const int bbase = (wn * 48 + l15) * 64;

    f32x4 acc[4][3] = {};
    bf16x8 afr[4], bfr[3][2];

#define STGA(bb, tt) { \
    _Pragma("unroll") for (int i_ = 0; i_ < 2; ++i_) \
        gload16(pA + (size_t)(tt) * 64 + i_ * 8192, Al[bb] + w * 1024 + i_ * 512); }
#define STGB(bb, tt) { \
    _Pragma("unroll") for (int j_ = 0; j_ < 3; ++j_) \
        gload16(pB + (size_t)(tt) * 64 + j_ * 8192, Bl[bb] + w * 1536 + j_ * 512); }

#define RDA(bb, G) \
    _Pragma("unroll") for (int mt_ = 0; mt_ < 4; ++mt_) \
        afr[mt_] = *(const bf16x8*)&Al[bb][abase + mt_ * 1024 + ((G) ? c1 : c0)];

#define RDB(bb) \
    _Pragma("unroll") for (int nt_ = 0; nt_ < 3; ++nt_) { \
        bfr[nt_][0] = *(const bf16x8*)&Bl[bb][bbase + nt_ * 1024 + c0]; \
        bfr[nt_][1] = *(const bf16x8*)&Bl[bb][bbase + nt_ * 1024 + c1]; }

#define MFMA12(G) \
    __builtin_amdgcn_s_setprio(1); \
    _Pragma("unroll") for (int mt_ = 0; mt_ < 4; ++mt_) \
    _Pragma("unroll") for (int nt_ = 0; nt_ < 3; ++nt_) \
        acc[mt_][nt_] = __builtin_amdgcn_mfma_f32_16x16x32_bf16( \
            afr[mt_], bfr[nt_][G], acc[mt_][nt_], 0, 0, 0); \
    __builtin_amdgcn_s_setprio(0);

#define BAR __builtin_amdgcn_s_barrier();
#define VMC3 { asm volatile("s_waitcnt vmcnt(3)" ::: "memory"); __builtin_amdgcn_sched_barrier(0); }
#define VMC0 { asm volatile("s_waitcnt vmcnt(0)" ::: "memory"); __builtin_amdgcn_sched_barrier(0); }

    // prologue: T0.B(3), T0.A(2), T1.B(3); drain T0, keep T1.SB in flight
    STGB(0, 0); STGA(0, 0); STGB(1, 1);
    VMC3; BAR;

#pragma unroll 1
    for (int t = 0; t < 8; ++t) {
        const bool nf = (t < 7);
        // p0: buf0 g0 (+ all B of buf0); stage T1.SA -> buf1.A
        RDA(0, 0) RDB(0)
        STGA(1, 2 * t + 1);
        BAR; MFMA12(0) BAR;
        // p1: buf0 g1; stage T2.SB -> buf0.B; drain T1
        RDA(0, 1)
        if (nf) STGB(0, 2 * t + 2);
        BAR; MFMA12(1)
        if (nf) { VMC3 } else { VMC0 }
        BAR;
        // p2: buf1 g0 (+ all B of buf1); stage T2.SA -> buf0.A
        RDA(1, 0) RDB(1)
        if (nf) STGA(0, 2 * t + 2);
        BAR; MFMA12(0) BAR;
        // p3: buf1 g1; stage T3.SB -> buf1.B; drain T2
        RDA(1, 1)
        if (nf) STGB(1, 2 * t + 3);
        BAR; MFMA12(1)
        if (nf) { VMC3 }
        BAR;
    }

    // ---- epilogue: scatter Q(x0.125*log2e)/K to [bh][s][hd], V^T [bh][hd][s]
#pragma unroll
    for (int mt = 0; mt < 4; ++mt) {
#pragma unroll
        for (int nt = 0; nt < 3; ++nt) {
            const int n_g = n0 + wn * 48 + nt * 16 + l15;
            const int m_b = m0 + wm * 64 + mt * 16 + lg * 4;
            const float bs = bias[n_g];
            const int which = n_g >> 10;          // 0=q 1=k 2=v
            const int nn = n_g & 1023;
            const int h = nn >> 6, hd = nn & 63;
            const int bb = m_b >> 11, s = m_b & 2047;
            if (which == 2) {
                ushort4 pv;
                pv.x = f2bf(acc[mt][nt][0] + bs);
                pv.y = f2bf(acc[mt][nt][1] + bs);
                pv.z = f2bf(acc[mt][nt][2] + bs);
                pv.w = f2bf(acc[mt][nt][3] + bs);
                *(ushort4*)&oV[((size_t)(bb * H_ + h) * HD_ + hd) * S_ + s] = pv;
            } else {
                u16* dst = which == 0 ? oQ : oK;
                const float scale = which == 0 ? (0.125f * LOG2E) : 1.0f;
#pragma unroll
                for (int r = 0; r < 4; ++r)
                    dst[((size_t)(bb * H_ + h) * S_ + s + r) * HD_ + hd] =
                        f2bf((acc[mt][nt][r] + bs) * scale);
            }
        }
    }
#undef STGA
#undef STGB
#undef RDA
#undef RDB
#undef MFMA12
#undef BAR
#undef VMC3
#undef VMC0
}

// ====== GEMM2: 64x128 tile, grid 512 (2 blocks/CU), 4-phase vmcnt ==========
// Per-wave 32x32. LDS 48KB: Al[2][64*64], Bl[2][128*64]. SA=1, SB=2 ->
// prologue vmcnt(2); p1/p3 vmcnt(2); vmcnt(0) only at t=7 boundary.
__global__ __launch_bounds__(512, 4) void gemm_proj2(
    const u16* __restrict__ A, const u16* __restrict__ Bt,
    const float* __restrict__ bias, float* __restrict__ oF) {
    extern __shared__ u16 lds[];
    u16* Al[2] = {lds, lds + 4096};                  // 64*64 each
    u16* Bl[2] = {lds + 8192, lds + 8192 + 8192};    // 128*64 each

    const int tid = threadIdx.x;
    const int lane = tid & 63, w = tid >> 6;
    const int wm = w >> 2, wn = w & 3;               // wave: 32m x 32n
    const int l15 = lane & 15, lg = lane >> 4;
    const int lin = blockIdx.y * 8 + blockIdx.x;     // grid (8,64)
    const int nl = (lin & 7) * 64 + (lin >> 3);      // XCD-chunked
    const int m0 = (nl >> 3) * 64, n0 = (nl & 7) * 128;

    const int lrow = lane >> 3;
    const int csrc = ((lane & 7) * 8) ^ ((lrow & 7) * 8);
    const u16* pA = A + (size_t)(m0 + w * 8 + lrow) * 1024 + csrc;
    const u16* pB = Bt + (size_t)(n0 + w * 16 + lrow) * 1024 + csrc;

    const int sw8 = (l15 & 7) * 8;
    const int c0 = (lg * 8) ^ sw8;
    const int c1 = (32 + lg * 8) ^ sw8;
    const int abase = (wm * 32 + l15) * 64;
    const int bbase = (wn * 32 + l15) * 64;

    f32x4 acc[2][2] = {};
    bf16x8 afr[2], bfr[2][2];

#define PSTGA(bb, tt) \
    gload16(pA + (size_t)(tt) * 64, Al[bb] + w * 512);
#define PSTGB(bb, tt) { \
    _Pragma("unroll") for (int i_ = 0; i_ < 2; ++i_) \
        gload16(pB + (size_t)(tt) * 64 + i_ * 8192, Bl[bb] + w * 1024 + i_ * 512); }

#define PRDA(bb, G) \
    _Pragma("unroll") for (int mt_ = 0; mt_ < 2; ++mt_) \
        afr[mt_] = *(const bf16x8*)&Al[bb][abase + mt_ * 1024 + ((G) ? c1 : c0)];

#define PRDB(bb) \
    _Pragma("unroll") for (int nt_ = 0; nt_ < 2; ++nt_) { \
        bfr[nt_][0] = *(const bf16x8*)&Bl[bb][bbase + nt_ * 1024 + c0]; \
        bfr[nt_][1] = *(const bf16x8*)&Bl[bb][bbase + nt_ * 1024 + c1]; }

#define PMFMA4(G) \
    __builtin_amdgcn_s_setprio(1); \
    _Pragma("unroll") for (int mt_ = 0; mt_ < 2; ++mt_) \
    _Pragma("unroll") for (int nt_ = 0; nt_ < 2; ++nt_) \
        acc[mt_][nt_] = __builtin_amdgcn_mfma_f32_16x16x32_bf16( \
            afr[mt_], bfr[nt_][G], acc[mt_][nt_], 0, 0, 0); \
    __builtin_amdgcn_s_setprio(0);

#define BAR __builtin_amdgcn_s_barrier();
#define VMC2 { asm volatile("s_waitcnt vmcnt(2)" ::: "memory"); __builtin_amdgcn_sched_barrier(0); }
#define VMC0 { asm volatile("s_waitcnt vmcnt(0)" ::: "memory"); __builtin_amdgcn_sched_barrier(0); }

    PSTGB(0, 0); PSTGA(0, 0); PSTGB(1, 1);
    VMC2; BAR;

#pragma unroll 1
    for (int t = 0; t < 8; ++t) {
        const bool nf = (t < 7);
        PRDA(0, 0) PRDB(0)
        PSTGA(1, 2 * t + 1);
        BAR; PMFMA4(0) BAR;
        PRDA(0, 1)
        if (nf) PSTGB(0, 2 * t + 2);
        BAR; PMFMA4(1)
        if (nf) { VMC2 } else { VMC0 }
        BAR;
        PRDA(1, 0) PRDB(1)
        if (nf) PSTGA(0, 2 * t + 2);
        BAR; PMFMA4(0) BAR;
        PRDA(1, 1)
        if (nf) PSTGB(1, 2 * t + 3);
        BAR; PMFMA4(1)
        if (nf) { VMC2 }
        BAR;
    }

#pragma unroll
    for (int mt = 0; mt < 2; ++mt)
#pragma unroll
        for (int nt = 0; nt < 2; ++nt) {
            const int n_g = n0 + wn * 32 + nt * 16 + l15;
            const int m_b = m0 + wm * 32 + mt * 16 + lg * 4;
            const float bs = bias[n_g];
#pragma unroll
            for (int r = 0; r < 4; ++r)
                oF[(size_t)(m_b + r) * 1024 + n_g] = acc[mt][nt][r] + bs;
        }
#undef PSTGA
#undef PSTGB
#undef PRDA
#undef PRDB
#undef PMFMA4
#undef BAR
#undef VMC2
#undef VMC0
}

// --- flash attention, causal, KVBLK=128, dual q-tile interleaved chains ----
__global__ __launch_bounds__(256, 2) void attn9(
    const u16* __restrict__ Q, const u16* __restrict__ Kp,
    const u16* __restrict__ VT, u16* __restrict__ Om) {
    extern __shared__ u16 lds[];
    u16* Kl = lds;            // 2 bufs x 8192 ([128][64])
    u16* Vl = lds + 16384;    // 2 bufs x 8192 ([64][128])
    u16* Pl = lds + 32768;    // 4 waves x 2048 ([16][128])
    const int tid = threadIdx.x;
    const int lane = tid & 63, w = tid >> 6;
    const int l15 = lane & 15, lg = lane >> 4;
    const int hw = blockIdx.x;
    const int bid = (hw & 7) * 64 + (hw >> 3);
    const int bh = bid >> 4, p = bid & 15;
    const int b = bh >> 4, h = bh & 15;
    const size_t baseK = (size_t)bh * (S_ * HD_);
    const u16* gk = Kp + baseK;
    const u16* gv = VT + (size_t)bh * (HD_ * S_);

    const int lrow = lane >> 3;
    const int csK = ((lane & 7) * 8) ^ ((lrow & 7) * 8);
    const int lg2 = lane >> 4;
    const int csV0 = ((lane & 15) * 8) ^ (lg2 * 8);
    const int csV1 = ((lane & 15) * 8) ^ ((4 + lg2) * 8);
    const u16* gkp[4];
    const u16* gvp[4];
#pragma unroll
    for (int i = 0; i < 4; ++i) {
        gkp[i] = gk + (size_t)(w * 32 + i * 8 + lrow) * HD_ + csK;
        gvp[i] = gv + (size_t)(w * 16 + i * 4 + lg2) * S_ + ((i & 1) ? csV1 : csV0);
    }
    u16* ldsK = Kl + w * 2048;
    u16* ldsV = Vl + w * 2048;

    const int sw = (l15 & 7) * 8;
    const int roK0 = l15 * 128 + 2 * ((lg * 8) ^ sw);
    const int roK1 = l15 * 128 + 2 * ((32 + lg * 8) ^ sw);
    int po[4];
#pragma unroll
    for (int g = 0; g < 4; ++g) po[g] = 2 * ((g * 32 + lg * 8) ^ sw);
    const char* kbase = (const char*)Kl;
    const char* vbase = (const char*)Vl;
    char* plw = (char*)(Pl + w * 2048);
    const int prb = l15 * 256;
    int pwo[8];
#pragma unroll
    for (int nt = 0; nt < 8; ++nt) pwo[nt] = prb + 2 * ((nt * 16 + lg * 4) ^ sw);

    const int qbA = 31 - p, qbB = p;
    const int kitA = (qbA + 2) >> 1, kitB = (qbB + 2) >> 1;
    const int qgA = qbA * 64 + w * 16 + l15;
    const int qgB = qbB * 64 + w * 16 + l15;

    const bf16x8 qa0 = *(const bf16x8*)&Q[baseK + (size_t)qgA * HD_ + lg * 8];
    const bf16x8 qa1 = *(const bf16x8*)&Q[baseK + (size_t)qgA * HD_ + 32 + lg * 8];
    const bf16x8 qb0 = *(const bf16x8*)&Q[baseK + (size_t)qgB * HD_ + lg * 8];
    const bf16x8 qb1 = *(const bf16x8*)&Q[baseK + (size_t)qgB * HD_ + 32 + lg * 8];

    f32x4 accA[4] = {}, accB[4] = {};
    float lA = 0.0f, lB = 0.0f;

#pragma unroll
    for (int i = 0; i < 4; ++i) {
        gload16(gkp[i], ldsK + i * 512);
        gload16(gvp[i], ldsV + i * 512);
    }

#define QK8(sc, q0v, q1v) { \
    _Pragma("unroll") for (int nt_ = 0; nt_ < 8; ++nt_) { \
        bf16x8 kf = *(const bf16x8*)(kb + nt_ * 2048 + roK0); \
        sc[nt_] = __builtin_amdgcn_mfma_f32_16x16x32_bf16(kf, q0v, f32x4{}, 0, 0, 0); } \
    _Pragma("unroll") for (int nt_ = 0; nt_ < 8; ++nt_) { \
        bf16x8 kf = *(const bf16x8*)(kb + nt_ * 2048 + roK1); \
        sc[nt_] = __builtin_amdgcn_mfma_f32_16x16x32_bf16(kf, q1v, sc[nt_], 0, 0, 0); } }

#define SMFIX(sc, lrun) { \
    float ps_ = 0.0f; \
    _Pragma("unroll") for (int nt_ = 0; nt_ < 8; ++nt_) { \
        float a_ = ex2(sc[nt_][0]); \
        float c_ = ex2(sc[nt_][1]); \
        float d_ = ex2(sc[nt_][2]); \
        float e_ = ex2(sc[nt_][3]); \
        sc[nt_][0] = a_; sc[nt_][1] = c_; sc[nt_][2] = d_; sc[nt_][3] = e_; \
        ps_ += (a_ + c_) + (d_ + e_); } \
    lrun += ps_; }

#define PWR(sc) { \
    _Pragma("unroll") for (int nt_ = 0; nt_ < 8; ++nt_) { \
        ushort4 pk_; \
        pk_.x = f2bf(sc[nt_][0]); pk_.y = f2bf(sc[nt_][1]); \
        pk_.z = f2bf(sc[nt_][2]); pk_.w = f2bf(sc[nt_][3]); \
        *(ushort4*)(plw + pwo[nt_]) = pk_; } }

#define PV8(accv) { \
    _Pragma("unroll") for (int g_ = 0; g_ < 4; ++g_) { \
        bf16x8 pb_ = *(const bf16x8*)(plw + prb + po[g_]); \
        _Pragma("unroll") for (int dt_ = 0; dt_ < 4; ++dt_) { \
            bf16x8 vf_ = *(const bf16x8*)(vb + (dt_ * 16 + l15) * 256 + po[g_]); \
            accv[dt_] = __builtin_amdgcn_mfma_f32_16x16x32_bf16(vf_, pb_, accv[dt_], 0, 0, 0); } } }

#define MASK8(sc, tc) { \
    _Pragma("unroll") for (int nt_ = 0; nt_ < 8; ++nt_) \
    _Pragma("unroll") for (int r_ = 0; r_ < 4; ++r_) \
        if (nt_ * 16 + lg * 4 + r_ > (tc)) sc[nt_][r_] = -1e30f; }

    for (int it = 0; it < kitA; ++it) {
        const int cur = it & 1;
        const int bo = cur * 16384;
        __syncthreads();
        if (it + 1 < kitA) {
            const int be = (cur ^ 1) * 8192;
            const int kt2 = (it + 1) * 128;
#pragma unroll
            for (int i = 0; i < 4; ++i) {
                gload16(gkp[i] + kt2 * HD_, ldsK + be + i * 512);
                gload16(gvp[i] + kt2, ldsV + be + i * 512);
            }
        }
        const char* kb = kbase + bo;
        const char* vb = vbase + bo;
        const bool doB = (it < kitB);

        f32x4 scA[8], scB[8];
        __builtin_amdgcn_s_setprio(1);
        QK8(scA, qa0, qa1)
        if (doB) QK8(scB, qb0, qb1)
        __builtin_amdgcn_s_setprio(0);
        if (it == kitA - 1) MASK8(scA, qgA - it * 128)
        if (doB && it == kitB - 1) MASK8(scB, qgB - it * 128)
        SMFIX(scA, lA)
        if (doB) SMFIX(scB, lB)
        PWR(scA)
        __builtin_amdgcn_s_setprio(1);
        PV8(accA)
        __builtin_amdgcn_s_setprio(0);
        if (doB) {
            PWR(scB)
            __builtin_amdgcn_s_setprio(1);
            PV8(accB)
            __builtin_amdgcn_s_setprio(0);
        }
    }
#undef QK8
#undef SMFIX
#undef PWR
#undef PV8
#undef MASK8

    {
        float lt = lA + __shfl_xor(lA, 16, 64);
        lt = lt + __shfl_xor(lt, 32, 64);
        const float rl = 1.0f / lt;
#pragma unroll
        for (int dt = 0; dt < 4; ++dt) {
            ushort4 ov;
            ov.x = f2bf(accA[dt][0] * rl);
            ov.y = f2bf(accA[dt][1] * rl);
            ov.z = f2bf(accA[dt][2] * rl);
            ov.w = f2bf(accA[dt][3] * rl);
            *(ushort4*)&Om[((size_t)b * S_ + qgA) * D_ + h * HD_ + dt * 16 + lg * 4] = ov;
        }
    }
    {
        float lt = lB + __shfl_xor(lB, 16, 64);
        lt = lt + __shfl_xor(lt, 32, 64);
        const float rl = 1.0f / lt;
#pragma unroll
        for (int dt = 0; dt < 4; ++dt) {
            ushort4 ov;
            ov.x = f2bf(accB[dt][0] * rl);
            ov.y = f2bf(accB[dt][1] * rl);
            ov.z = f2bf(accB[dt][2] * rl);
            ov.w = f2bf(accB[dt][3] * rl);
            *(ushort4*)&Om[((size_t)b * S_ + qgB) * D_ + h * HD_ + dt * 16 + lg * 4] = ov;
        }
    }
}

extern "C" void kernel_launch(void* const* d_in, const int* in_sizes, int n_in,
                              void* d_out, int out_size, void* d_ws, size_t ws_size,
                              hipStream_t stream) {
    const float* x      = (const float*)d_in[0];
    const float* w_attn = (const float*)d_in[1];
    const float* b_attn = (const float*)d_in[2];
    const float* w_proj = (const float*)d_in[3];
    const float* b_proj = (const float*)d_in[4];
    float* out = (float*)d_out;

    char* ws = (char*)d_ws;
    const size_t XE = (size_t)B_ * S_ * D_;          // 4194304
    u16* x_bf = (u16*)ws;            ws += XE * 2;   // reused as merged
    u16* waT  = (u16*)ws;            ws += (size_t)3 * D_ * D_ * 2;
    u16* wpT  = (u16*)ws;            ws += (size_t)D_ * D_ * 2;
    u16* Qb   = (u16*)ws;            ws += XE * 2;
    u16* Kb   = (u16*)ws;            ws += XE * 2;
    u16* Vt   = (u16*)ws;            ws += XE * 2;   // [bh][hd][s]
    u16* Mg   = x_bf;                // alias: x_bf dead after GEMM1

    hipFuncSetAttribute((const void*)gemm192b,
                        hipFuncAttributeMaxDynamicSharedMemorySize, 81920);
    hipFuncSetAttribute((const void*)attn9,
                        hipFuncAttributeMaxDynamicSharedMemorySize, 81920);
    hipFuncSetAttribute((const void*)gemm_proj2,
                        hipFuncAttributeMaxDynamicSharedMemorySize, 49152);

    prep<<<8192, 256, 0, stream>>>(x, x_bf, w_attn, waT, w_proj, wpT);

    gemm192b<<<dim3(16, 32), 512, 81920, stream>>>(x_bf, waT, b_attn, Qb, Kb, Vt);

    attn9<<<B_ * H_ * 16, 256, 81920, stream>>>(Qb, Kb, Vt, Mg);

    gemm_proj2<<<dim3(8, 64), 512, 49152, stream>>>(Mg, wpT, b_proj, out);
}

// Round 14
// 90.713 us; speedup vs baseline: 1.0227x; 1.0227x over previous
//
#include <hip/hip_runtime.h>
#include <hip/hip_bf16.h>

typedef __attribute__((ext_vector_type(8))) short bf16x8;
typedef __attribute__((ext_vector_type(4))) float f32x4;
typedef unsigned short u16;
typedef unsigned int u32;

#define B_ 2
#define S_ 2048
#define D_ 1024
#define H_ 16
#define HD_ 64

#define LOG2E 1.44269504088896340736f

__device__ __forceinline__ u16 f2bf(float f) {
    __hip_bfloat16 h = __float2bfloat16(f);
    u16 r;
    __builtin_memcpy(&r, &h, 2);
    return r;
}

__device__ __forceinline__ float ex2(float x) {
    float r;
    asm("v_exp_f32 %0, %1" : "=v"(r) : "v"(x));
    return r;
}

__device__ __forceinline__ void gload16(const u16* gsrc, u16* lds_base) {
    __builtin_amdgcn_global_load_lds(
        (const __attribute__((address_space(1))) void*)gsrc,
        (__attribute__((address_space(3))) void*)lds_base, 16, 0, 0);
}

// ---------------- prep: x->bf16, w_attn^T->bf16, w_proj^T->bf16 (1 launch) --
__global__ __launch_bounds__(256) void prep(
    const float* __restrict__ x, u16* __restrict__ x_bf,
    const float* __restrict__ wa, u16* __restrict__ waT,
    const float* __restrict__ wp, u16* __restrict__ wpT) {
    __shared__ float t[32][33];
    const int bid = blockIdx.x;
    const int tid = threadIdx.x;
    if (bid < 4096) {
        int i = bid * 256 + tid;
        float4 v = ((const float4*)x)[i];
        ushort4 o;
        o.x = f2bf(v.x); o.y = f2bf(v.y); o.z = f2bf(v.z); o.w = f2bf(v.w);
        ((ushort4*)x_bf)[i] = o;
        return;
    }
    const float* in;
    u16* out;
    int R = 1024, C, bx, by;
    if (bid < 4096 + 3072) {
        in = wa; out = waT; C = 3072;
        int idx = bid - 4096;
        bx = idx % 96; by = idx / 96;
    } else {
        in = wp; out = wpT; C = 1024;
        int idx = bid - 7168;
        bx = idx % 32; by = idx / 32;
    }
    const int c0 = bx * 32, r0 = by * 32;
    const int lx = tid & 31, ly = tid >> 5;
#pragma unroll
    for (int i = 0; i < 4; ++i)
        t[ly + i * 8][lx] = in[(size_t)(r0 + ly + i * 8) * C + c0 + lx];
    __syncthreads();
#pragma unroll
    for (int i = 0; i < 4; ++i)
        out[(size_t)(c0 + ly + i * 8) * R + r0 + lx] = f2bf(t[lx][ly + i * 8]);
}

// ============ GEMM1: 256x192 tile, 4-phase counted-vmcnt schedule ==========
__global__ __launch_bounds__(512, 1) void gemm192(
    const u16* __restrict__ A, const u16* __restrict__ Bt,
    const float* __restrict__ bias,
    u16* __restrict__ oQ, u16* __restrict__ oK, u16* __restrict__ oV) {
    extern __shared__ u16 lds[];
    u16* Al[2] = {lds, lds + 16384};
    u16* Bl[2] = {lds + 32768, lds + 32768 + 12288};

    const int tid = threadIdx.x;
    const int lane = tid & 63, w = tid >> 6;
    const int wm = w >> 2, wn = w & 3;
    const int l15 = lane & 15, lg = lane >> 4;
    const int lin = blockIdx.y * 16 + blockIdx.x;
    const int nl = (lin & 7) * 32 + (lin >> 3);
    const int m0 = (nl >> 4) * 256, n0 = (nl & 15) * 192;

    const int lrow = lane >> 3;
    const int csrc = ((lane & 7) * 8) ^ ((lrow & 7) * 8);
    const u16* pA = A + (size_t)(m0 + w * 32 + lrow) * 1024 + csrc;
    const u16* pB = Bt + (size_t)(n0 + w * 24 + lrow) * 1024 + csrc;

    const int sw8 = (l15 & 7) * 8;
    const int c0 = (lg * 8) ^ sw8;
    const int c1 = (32 + lg * 8) ^ sw8;
    const int abase = (wm * 128 + l15) * 64;
    const int bbase = (wn * 48 + l15) * 64;

    f32x4 acc[8][3] = {};
    bf16x8 afr[4][2], bfr[3][2];

#define STGA(bb, tt) { \
    _Pragma("unroll") for (int i_ = 0; i_ < 4; ++i_) \
        gload16(pA + (size_t)(tt) * 64 + i_ * 8192, Al[bb] + w * 2048 + i_ * 512); }
#define STGB(bb, tt) { \
    _Pragma("unroll") for (int j_ = 0; j_ < 3; ++j_) \
        gload16(pB + (size_t)(tt) * 64 + j_ * 8192, Bl[bb] + w * 1536 + j_ * 512); }

#define RDA(bb, AH) \
    _Pragma("unroll") for (int mt_ = 0; mt_ < 4; ++mt_) { \
        afr[mt_][0] = *(const bf16x8*)&Al[bb][abase + (AH) * 4096 + mt_ * 1024 + c0]; \
        afr[mt_][1] = *(const bf16x8*)&Al[bb][abase + (AH) * 4096 + mt_ * 1024 + c1]; }

#define RDB(bb) \
    _Pragma("unroll") for (int nt_ = 0; nt_ < 3; ++nt_) { \
        bfr[nt_][0] = *(const bf16x8*)&Bl[bb][bbase + nt_ * 1024 + c0]; \
        bfr[nt_][1] = *(const bf16x8*)&Bl[bb][bbase + nt_ * 1024 + c1]; }

#define MFMA24(AH) \
    __builtin_amdgcn_s_setprio(1); \
    _Pragma("unroll") for (int mt_ = 0; mt_ < 4; ++mt_) \
    _Pragma("unroll") for (int nt_ = 0; nt_ < 3; ++nt_) { \
        acc[(AH)*4+mt_][nt_] = __builtin_amdgcn_mfma_f32_16x16x32_bf16( \
            afr[mt_][0], bfr[nt_][0], acc[(AH)*4+mt_][nt_], 0, 0, 0); \
        acc[(AH)*4+mt_][nt_] = __builtin_amdgcn_mfma_f32_16x16x32_bf16( \
            afr[mt_][1], bfr[nt_][1], acc[(AH)*4+mt_][nt_], 0, 0, 0); } \
    __builtin_amdgcn_s_setprio(0);

#define BAR __builtin_amdgcn_s_barrier();
#define VMC3 { asm volatile("s_waitcnt vmcnt(3)" ::: "memory"); __builtin_amdgcn_sched_barrier(0); }
#define VMC0 { asm volatile("s_waitcnt vmcnt(0)" ::: "memory"); __builtin_amdgcn_sched_barrier(0); }

    STGB(0, 0); STGA(0, 0); STGB(1, 1);
    VMC3; BAR;

#pragma unroll 1
    for (int t = 0; t < 8; ++t) {
        const bool nf = (t < 7);
        RDA(0, 0) RDB(0)
        STGA(1, 2 * t + 1);
        BAR; MFMA24(0) BAR;
        RDA(0, 1)
        if (nf) STGB(0, 2 * t + 2);
        BAR; MFMA24(1)
        if (nf) { VMC3 } else { VMC0 }
        BAR;
        RDA(1, 0) RDB(1)
        if (nf) STGA(0, 2 * t + 2);
        BAR; MFMA24(0) BAR;
        RDA(1, 1)
        if (nf) STGB(1, 2 * t + 3);
        BAR; MFMA24(1)
        if (nf) { VMC3 }
        BAR;
    }

#pragma unroll
    for (int mt = 0; mt < 8; ++mt) {
#pragma unroll
        for (int nt = 0; nt < 3; ++nt) {
            const int n_g = n0 + wn * 48 + nt * 16 + l15;
            const int m_b = m0 + wm * 128 + mt * 16 + lg * 4;
            const float bs = bias[n_g];
            const int which = n_g >> 10;
            const int nn = n_g & 1023;
            const int h = nn >> 6, hd = nn & 63;
            const int bb = m_b >> 11, s = m_b & 2047;
            if (which == 2) {
                ushort4 pv;
                pv.x = f2bf(acc[mt][nt][0] + bs);
                pv.y = f2bf(acc[mt][nt][1] + bs);
                pv.z = f2bf(acc[mt][nt][2] + bs);
                pv.w = f2bf(acc[mt][nt][3] + bs);
                *(ushort4*)&oV[((size_t)(bb * H_ + h) * HD_ + hd) * S_ + s] = pv;
            } else {
                u16* dst = which == 0 ? oQ : oK;
                const float scale = which == 0 ? (0.125f * LOG2E) : 1.0f;
#pragma unroll
                for (int r = 0; r < 4; ++r)
                    dst[((size_t)(bb * H_ + h) * S_ + s + r) * HD_ + hd] =
                        f2bf((acc[mt][nt][r] + bs) * scale);
            }
        }
    }
#undef STGA
#undef STGB
#undef RDA
#undef RDB
#undef MFMA24
#undef BAR
#undef VMC3
#undef VMC0
}

// ===== GEMM2: 128x128 tile, 8 waves, 4-phase counted-vmcnt (out fp32) ======
__global__ __launch_bounds__(512, 1) void gemm_proj(
    const u16* __restrict__ A, const u16* __restrict__ Bt,
    const float* __restrict__ bias, float* __restrict__ oF) {
    extern __shared__ u16 lds[];
    u16* Al[2] = {lds, lds + 8192};
    u16* Bl[2] = {lds + 16384, lds + 16384 + 8192};

    const int tid = threadIdx.x;
    const int lane = tid & 63, w = tid >> 6;
    const int wm = w >> 2, wn = w & 3;
    const int l15 = lane & 15, lg = lane >> 4;
    const int lin = blockIdx.y * 8 + blockIdx.x;
    const int nl = (lin & 7) * 32 + (lin >> 3);
    const int m0 = (nl >> 3) * 128, n0 = (nl & 7) * 128;

    const int lrow = lane >> 3;
    const int csrc = ((lane & 7) * 8) ^ ((lrow & 7) * 8);
    const u16* pA = A + (size_t)(m0 + w * 16 + lrow) * 1024 + csrc;
    const u16* pB = Bt + (size_t)(n0 + w * 16 + lrow) * 1024 + csrc;

    const int sw8 = (l15 & 7) * 8;
    const int c0 = (lg * 8) ^ sw8;
    const int c1 = (32 + lg * 8) ^ sw8;
    const int abase = (wm * 64 + l15) * 64;
    const int bbase = (wn * 32 + l15) * 64;

    f32x4 acc[4][2] = {};
    bf16x8 afr[4], bfr[2][2];

#define PSTGA(bb, tt) { \
    _Pragma("unroll") for (int i_ = 0; i_ < 2; ++i_) \
        gload16(pA + (size_t)(tt) * 64 + i_ * 8192, Al[bb] + w * 1024 + i_ * 512); }
#define PSTGB(bb, tt) { \
    _Pragma("unroll") for (int i_ = 0; i_ < 2; ++i_) \
        gload16(pB + (size_t)(tt) * 64 + i_ * 8192, Bl[bb] + w * 1024 + i_ * 512); }

#define PRDA(bb, G) \
    _Pragma("unroll") for (int mt_ = 0; mt_ < 4; ++mt_) \
        afr[mt_] = *(const bf16x8*)&Al[bb][abase + mt_ * 1024 + ((G) ? c1 : c0)];

#define PRDB(bb) \
    _Pragma("unroll") for (int nt_ = 0; nt_ < 2; ++nt_) { \
        bfr[nt_][0] = *(const bf16x8*)&Bl[bb][bbase + nt_ * 1024 + c0]; \
        bfr[nt_][1] = *(const bf16x8*)&Bl[bb][bbase + nt_ * 1024 + c1]; }

#define PMFMA8(G) \
    __builtin_amdgcn_s_setprio(1); \
    _Pragma("unroll") for (int mt_ = 0; mt_ < 4; ++mt_) \
    _Pragma("unroll") for (int nt_ = 0; nt_ < 2; ++nt_) \
        acc[mt_][nt_] = __builtin_amdgcn_mfma_f32_16x16x32_bf16( \
            afr[mt_], bfr[nt_][G], acc[mt_][nt_], 0, 0, 0); \
    __builtin_amdgcn_s_setprio(0);

#define BAR __builtin_amdgcn_s_barrier();
#define VMC2 { asm volatile("s_waitcnt vmcnt(2)" ::: "memory"); __builtin_amdgcn_sched_barrier(0); }
#define VMC0 { asm volatile("s_waitcnt vmcnt(0)" ::: "memory"); __builtin_amdgcn_sched_barrier(0); }

    PSTGB(0, 0); PSTGA(0, 0); PSTGB(1, 1);
    VMC2; BAR;

#pragma unroll 1
    for (int t = 0; t < 8; ++t) {
        const bool nf = (t < 7);
        PRDA(0, 0) PRDB(0)
        PSTGA(1, 2 * t + 1);
        BAR; PMFMA8(0) BAR;
        PRDA(0, 1)
        if (nf) PSTGB(0, 2 * t + 2);
        BAR; PMFMA8(1)
        if (nf) { VMC2 } else { VMC0 }
        BAR;
        PRDA(1, 0) PRDB(1)
        if (nf) PSTGA(0, 2 * t + 2);
        BAR; PMFMA8(0) BAR;
        PRDA(1, 1)
        if (nf) PSTGB(1, 2 * t + 3);
        BAR; PMFMA8(1)
        if (nf) { VMC2 }
        BAR;
    }

#pragma unroll
    for (int mt = 0; mt < 4; ++mt)
#pragma unroll
        for (int nt = 0; nt < 2; ++nt) {
            const int n_g = n0 + wn * 32 + nt * 16 + l15;
            const int m_b = m0 + wm * 64 + mt * 16 + lg * 4;
            const float bs = bias[n_g];
#pragma unroll
            for (int r = 0; r < 4; ++r)
                oF[(size_t)(m_b + r) * 1024 + n_g] = acc[mt][nt][r] + bs;
        }
#undef PSTGA
#undef PSTGB
#undef PRDA
#undef PRDB
#undef PMFMA8
#undef BAR
#undef VMC2
#undef VMC0
}

// --- flash attention, causal, KVBLK=128, dual q-tile interleaved chains ----
// R14 reorder: PWR_A issues before SMFIX_B so P-writes' lgkm latency drains
// under chain-B's v_exp burst; PV_A then reads with writes already landed.
__global__ __launch_bounds__(256, 2) void attn9(
    const u16* __restrict__ Q, const u16* __restrict__ Kp,
    const u16* __restrict__ VT, u16* __restrict__ Om) {
    extern __shared__ u16 lds[];
    u16* Kl = lds;            // 2 bufs x 8192 ([128][64])
    u16* Vl = lds + 16384;    // 2 bufs x 8192 ([64][128])
    u16* Pl = lds + 32768;    // 4 waves x 2048 ([16][128])
    const int tid = threadIdx.x;
    const int lane = tid & 63, w = tid >> 6;
    const int l15 = lane & 15, lg = lane >> 4;
    const int hw = blockIdx.x;
    const int bid = (hw & 7) * 64 + (hw >> 3);
    const int bh = bid >> 4, p = bid & 15;
    const int b = bh >> 4, h = bh & 15;
    const size_t baseK = (size_t)bh * (S_ * HD_);
    const u16* gk = Kp + baseK;
    const u16* gv = VT + (size_t)bh * (HD_ * S_);

    const int lrow = lane >> 3;
    const int csK = ((lane & 7) * 8) ^ ((lrow & 7) * 8);
    const int lg2 = lane >> 4;
    const int csV0 = ((lane & 15) * 8) ^ (lg2 * 8);
    const int csV1 = ((lane & 15) * 8) ^ ((4 + lg2) * 8);
    const u16* gkp[4];
    const u16* gvp[4];
#pragma unroll
    for (int i = 0; i < 4; ++i) {
        gkp[i] = gk + (size_t)(w * 32 + i * 8 + lrow) * HD_ + csK;
        gvp[i] = gv + (size_t)(w * 16 + i * 4 + lg2) * S_ + ((i & 1) ? csV1 : csV0);
    }
    u16* ldsK = Kl + w * 2048;
    u16* ldsV = Vl + w * 2048;

    const int sw = (l15 & 7) * 8;
    const int roK0 = l15 * 128 + 2 * ((lg * 8) ^ sw);
    const int roK1 = l15 * 128 + 2 * ((32 + lg * 8) ^ sw);
    int po[4];
#pragma unroll
    for (int g = 0; g < 4; ++g) po[g] = 2 * ((g * 32 + lg * 8) ^ sw);
    const char* kbase = (const char*)Kl;
    const char* vbase = (const char*)Vl;
    char* plw = (char*)(Pl + w * 2048);
    const int prb = l15 * 256;
    int pwo[8];
#pragma unroll
    for (int nt = 0; nt < 8; ++nt) pwo[nt] = prb + 2 * ((nt * 16 + lg * 4) ^ sw);

    const int qbA = 31 - p, qbB = p;
    const int kitA = (qbA + 2) >> 1, kitB = (qbB + 2) >> 1;
    const int qgA = qbA * 64 + w * 16 + l15;
    const int qgB = qbB * 64 + w * 16 + l15;

    const bf16x8 qa0 = *(const bf16x8*)&Q[baseK + (size_t)qgA * HD_ + lg * 8];
    const bf16x8 qa1 = *(const bf16x8*)&Q[baseK + (size_t)qgA * HD_ + 32 + lg * 8];
    const bf16x8 qb0 = *(const bf16x8*)&Q[baseK + (size_t)qgB * HD_ + lg * 8];
    const bf16x8 qb1 = *(const bf16x8*)&Q[baseK + (size_t)qgB * HD_ + 32 + lg * 8];

    f32x4 accA[4] = {}, accB[4] = {};
    float lA = 0.0f, lB = 0.0f;

#pragma unroll
    for (int i = 0; i < 4; ++i) {
        gload16(gkp[i], ldsK + i * 512);
        gload16(gvp[i], ldsV + i * 512);
    }

#define QK8(sc, q0v, q1v) { \
    _Pragma("unroll") for (int nt_ = 0; nt_ < 8; ++nt_) { \
        bf16x8 kf = *(const bf16x8*)(kb + nt_ * 2048 + roK0); \
        sc[nt_] = __builtin_amdgcn_mfma_f32_16x16x32_bf16(kf, q0v, f32x4{}, 0, 0, 0); } \
    _Pragma("unroll") for (int nt_ = 0; nt_ < 8; ++nt_) { \
        bf16x8 kf = *(const bf16x8*)(kb + nt_ * 2048 + roK1); \
        sc[nt_] = __builtin_amdgcn_mfma_f32_16x16x32_bf16(kf, q1v, sc[nt_], 0, 0, 0); } }

#define SMFIX(sc, lrun) { \
    float ps_ = 0.0f; \
    _Pragma("unroll") for (int nt_ = 0; nt_ < 8; ++nt_) { \
        float a_ = ex2(sc[nt_][0]); \
        float c_ = ex2(sc[nt_][1]); \
        float d_ = ex2(sc[nt_][2]); \
        float e_ = ex2(sc[nt_][3]); \
        sc[nt_][0] = a_; sc[nt_][1] = c_; sc[nt_][2] = d_; sc[nt_][3] = e_; \
        ps_ += (a_ + c_) + (d_ + e_); } \
    lrun += ps_; }

#define PWR(sc) { \
    _Pragma("unroll") for (int nt_ = 0; nt_ < 8; ++nt_) { \
        ushort4 pk_; \
        pk_.x = f2bf(sc[nt_][0]); pk_.y = f2bf(sc[nt_][1]); \
        pk_.z = f2bf(sc[nt_][2]); pk_.w = f2bf(sc[nt_][3]); \
        *(ushort4*)(plw + pwo[nt_]) = pk_; } }

#define PV8(accv) { \
    _Pragma("unroll") for (int g_ = 0; g_ < 4; ++g_) { \
        bf16x8 pb_ = *(const bf16x8*)(plw + prb + po[g_]); \
        _Pragma("unroll") for (int dt_ = 0; dt_ < 4; ++dt_) { \
            bf16x8 vf_ = *(const bf16x8*)(vb + (dt_ * 16 + l15) * 256 + po[g_]); \
            accv[dt_] = __builtin_amdgcn_mfma_f32_16x16x32_bf16(vf_, pb_, accv[dt_], 0, 0, 0); } } }

#define MASK8(sc, tc) { \
    _Pragma("unroll") for (int nt_ = 0; nt_ < 8; ++nt_) \
    _Pragma("unroll") for (int r_ = 0; r_ < 4; ++r_) \
        if (nt_ * 16 + lg * 4 + r_ > (tc)) sc[nt_][r_] = -1e30f; }

    for (int it = 0; it < kitA; ++it) {
        const int cur = it & 1;
        const int bo = cur * 16384;
        __syncthreads();
        if (it + 1 < kitA) {
            const int be = (cur ^ 1) * 8192;
            const int kt2 = (it + 1) * 128;
#pragma unroll
            for (int i = 0; i < 4; ++i) {
                gload16(gkp[i] + kt2 * HD_, ldsK + be + i * 512);
                gload16(gvp[i] + kt2, ldsV + be + i * 512);
            }
        }
        const char* kb = kbase + bo;
        const char* vb = vbase + bo;
        const bool doB = (it < kitB);

        f32x4 scA[8], scB[8];
        __builtin_amdgcn_s_setprio(1);
        QK8(scA, qa0, qa1)
        if (doB) QK8(scB, qb0, qb1)
        __builtin_amdgcn_s_setprio(0);
        if (it == kitA - 1) MASK8(scA, qgA - it * 128)
        if (doB && it == kitB - 1) MASK8(scB, qgB - it * 128)
        // A's softmax + P-write first; B's softmax covers the P-write lgkm.
        SMFIX(scA, lA)
        PWR(scA)
        if (doB) SMFIX(scB, lB)
        __builtin_amdgcn_s_setprio(1);
        PV8(accA)
        __builtin_amdgcn_s_setprio(0);
        if (doB) {
            PWR(scB)
            __builtin_amdgcn_s_setprio(1);
            PV8(accB)
            __builtin_amdgcn_s_setprio(0);
        }
    }
#undef QK8
#undef SMFIX
#undef PWR
#undef PV8
#undef MASK8

    {
        float lt = lA + __shfl_xor(lA, 16, 64);
        lt = lt + __shfl_xor(lt, 32, 64);
        const float rl = 1.0f / lt;
#pragma unroll
        for (int dt = 0; dt < 4; ++dt) {
            ushort4 ov;
            ov.x = f2bf(accA[dt][0] * rl);
            ov.y = f2bf(accA[dt][1] * rl);
            ov.z = f2bf(accA[dt][2] * rl);
            ov.w = f2bf(accA[dt][3] * rl);
            *(ushort4*)&Om[((size_t)b * S_ + qgA) * D_ + h * HD_ + dt * 16 + lg * 4] = ov;
        }
    }
    {
        float lt = lB + __shfl_xor(lB, 16, 64);
        lt = lt + __shfl_xor(lt, 32, 64);
        const float rl = 1.0f / lt;
#pragma unroll
        for (int dt = 0; dt < 4; ++dt) {
            ushort4 ov;
            ov.x = f2bf(accB[dt][0] * rl);
            ov.y = f2bf(accB[dt][1] * rl);
            ov.z = f2bf(accB[dt][2] * rl);
            ov.w = f2bf(accB[dt][3] * rl);
            *(ushort4*)&Om[((size_t)b * S_ + qgB) * D_ + h * HD_ + dt * 16 + lg * 4] = ov;
        }
    }
}

extern "C" void kernel_launch(void* const* d_in, const int* in_sizes, int n_in,
                              void* d_out, int out_size, void* d_ws, size_t ws_size,
                              hipStream_t stream) {
    const float* x      = (const float*)d_in[0];
    const float* w_attn = (const float*)d_in[1];
    const float* b_attn = (const float*)d_in[2];
    const float* w_proj = (const float*)d_in[3];
    const float* b_proj = (const float*)d_in[4];
    float* out = (float*)d_out;

    char* ws = (char*)d_ws;
    const size_t XE = (size_t)B_ * S_ * D_;          // 4194304
    u16* x_bf = (u16*)ws;            ws += XE * 2;   // reused as merged
    u16* waT  = (u16*)ws;            ws += (size_t)3 * D_ * D_ * 2;
    u16* wpT  = (u16*)ws;            ws += (size_t)D_ * D_ * 2;
    u16* Qb   = (u16*)ws;            ws += XE * 2;
    u16* Kb   = (u16*)ws;            ws += XE * 2;
    u16* Vt   = (u16*)ws;            ws += XE * 2;   // [bh][hd][s]
    u16* Mg   = x_bf;                // alias: x_bf dead after GEMM1

    hipFuncSetAttribute((const void*)gemm192,
                        hipFuncAttributeMaxDynamicSharedMemorySize, 114688);
    hipFuncSetAttribute((const void*)attn9,
                        hipFuncAttributeMaxDynamicSharedMemorySize, 81920);
    hipFuncSetAttribute((const void*)gemm_proj,
                        hipFuncAttributeMaxDynamicSharedMemorySize, 65536);

    prep<<<8192, 256, 0, stream>>>(x, x_bf, w_attn, waT, w_proj, wpT);

    gemm192<<<dim3(16, 16), 512, 114688, stream>>>(x_bf, waT, b_attn, Qb, Kb, Vt);

    attn9<<<B_ * H_ * 16, 256, 81920, stream>>>(Qb, Kb, Vt, Mg);

    gemm_proj<<<dim3(8, 32), 512, 65536, stream>>>(Mg, wpT, b_proj, out);
}